// Round 13
// baseline (294.830 us; speedup 1.0000x reference)
//
#include <hip/hip_runtime.h>
#include <hip/hip_bf16.h>
#include <cstdint>

#define D_MODEL 4096
#define NFIB    64
#define NBATCH  4
#define LSEQ    4096
#define NTOK    (NBATCH * LSEQ)

typedef __attribute__((ext_vector_type(4))) float f32x4;
typedef __attribute__((ext_vector_type(8))) short bf16x8;

__device__ __forceinline__ unsigned short f2bf(float f) {
  unsigned int u = __builtin_bit_cast(unsigned int, f);
  u += 0x7FFFu + ((u >> 16) & 1u);
  return (unsigned short)(u >> 16);
}
__device__ __forceinline__ float bf2f(unsigned short u) {
  return __builtin_bit_cast(float, (uint32_t)u << 16);
}
__device__ __forceinline__ bf16x8 cvt8(f32x4 a, f32x4 b) {
  union { __hip_bfloat162 h2[4]; bf16x8 v; } u;
  u.h2[0] = __float22bfloat162_rn(make_float2(a[0], a[1]));
  u.h2[1] = __float22bfloat162_rn(make_float2(a[2], a[3]));
  u.h2[2] = __float22bfloat162_rn(make_float2(b[0], b[1]));
  u.h2[3] = __float22bfloat162_rn(make_float2(b[2], b[3]));
  return u.v;
}

#define SB __builtin_amdgcn_sched_barrier(0)
#define WAITV(N)                                              \
  asm volatile("s_waitcnt vmcnt(" #N ")" ::: "memory");       \
  SB

// ---------------------------------------------------------------------------
// Blocks 0..3: S_b = Q_b - I = 2(I-A)^{-1}A.  Blocks 4..1027: Wd -> Wd2.
// ---------------------------------------------------------------------------
__global__ __launch_bounds__(256) void prep1_kernel(const float* __restrict__ A,
                                                    const float* __restrict__ Wd,
                                                    float* __restrict__ S,
                                                    unsigned short* __restrict__ Wd2) {
  const int blk = blockIdx.x;
  if (blk >= NBATCH) {
    int idx = (blk - NBATCH) * 256 + threadIdx.x;
    int j    = idx & 7;
    int lane = (idx >> 3) & 63;
    int nf   = (idx >> 9) & 3;
    int ks   = idx >> 11;
    int row = nf * 16 + (lane & 15);
    int col = ks * 32 + (lane >> 4) * 8 + j;
    Wd2[idx] = f2bf(Wd[row * D_MODEL + col]);
    return;
  }
  __shared__ float M[64][66];
  __shared__ float R[64][66];
  const int b = blk;
  const int tid = threadIdx.x;
  const int k = tid & 63;
  const int g = tid >> 6;
  const float* Ab = A + b * 4096;
#pragma unroll
  for (int ii = 0; ii < 16; ++ii) {
    int i = g * 16 + ii;
    float a = Ab[i * 64 + k];
    M[i][k] = ((i == k) ? 1.0f : 0.0f) - a;
    R[i][k] = 2.0f * a;
  }
  for (int j = 0; j < 64; ++j) {
    __syncthreads();
    float pr  = 1.0f / M[j][j];
    float mjk = M[j][k], rjk = R[j][k];
    float f[16];
#pragma unroll
    for (int ii = 0; ii < 16; ++ii) f[ii] = M[g * 16 + ii][j] * pr;
    __syncthreads();
#pragma unroll
    for (int ii = 0; ii < 16; ++ii) {
      int i = g * 16 + ii;
      if (i != j) { M[i][k] -= f[ii] * mjk; R[i][k] -= f[ii] * rjk; }
    }
  }
  __syncthreads();
  float* Sb = S + b * 4096;
#pragma unroll
  for (int ii = 0; ii < 16; ++ii) {
    int i = g * 16 + ii;
    Sb[i * 64 + k] = R[i][k] / M[i][i];
  }
}

// ---------------------------------------------------------------------------
// U2[(((b*256+nt)*64+lane)*2+h)*8+j] = bf16(alpha*(Wup@S)[d][f])
// ---------------------------------------------------------------------------
__global__ __launch_bounds__(256) void prep_u_kernel(const float* __restrict__ Wup,
                                                     const float* __restrict__ S,
                                                     const float* __restrict__ alpha_p,
                                                     unsigned short* __restrict__ U2) {
  __shared__ float Sl[4096];
  const int blk = blockIdx.x;          // 0..511
  const int b = blk >> 7;
  const int ntg = blk & 127;
  const float* Sb = S + b * 4096;
  for (int i = threadIdx.x; i < 1024; i += 256)
    ((f32x4*)Sl)[i] = ((const f32x4*)Sb)[i];
  __syncthreads();

  const int t = threadIdx.x;
  const int nt   = ntg * 2 + (t >> 7);
  const int h    = (t >> 6) & 1;
  const int lane = t & 63;
  const int d = nt * 16 + (lane & 15);
  const int fbase = h * 32 + (lane >> 4) * 8;
  const float alpha = alpha_p[0];
  const f32x4* wr = (const f32x4*)(Wup + d * 64);

  float s[8];
#pragma unroll
  for (int j = 0; j < 8; ++j) s[j] = 0.f;
#pragma unroll
  for (int g4 = 0; g4 < 16; ++g4) {
    f32x4 wv = wr[g4];
#pragma unroll
    for (int gg = 0; gg < 4; ++gg) {
      const float* srow = &Sl[(g4 * 4 + gg) * 64 + fbase];
      float wvg = wv[gg];
#pragma unroll
      for (int j = 0; j < 8; ++j) s[j] += wvg * srow[j];
    }
  }
  bf16x8 v;
#pragma unroll
  for (int j = 0; j < 8; ++j) v[j] = (short)f2bf(alpha * s[j]);
  *(bf16x8*)(U2 + ((((size_t)b * 256 + nt) * 64 + lane) * 2 + h) * 8) = v;
}

// ---------------------------------------------------------------------------
// Fused main. Block = 16 tokens, 4 waves, grid 1024. Barrier-free per-wave
// deep gload_lds rings (4 slots x 2KB), counted vmcnt(18) = 3 groups in
// flight; every section fenced with sched_barrier so the static counts hold.
// Phase 1: wave w = K-strip w*1024; F reduce via LDS bf16 partials.
// Phase 2: wave w = col-strip w*1024; residual ring + U(L2) + MFMA + store.
// XOR swizzle (row&7)<<4 applied on global source AND LDS reads.
// ---------------------------------------------------------------------------
__global__ __launch_bounds__(256, 4) void fused_kernel(
    const float* __restrict__ H, const unsigned short* __restrict__ Wd2,
    const unsigned short* __restrict__ U2, float* __restrict__ Out) {
  const int blk = blockIdx.x;
  const int row0 = blk * 16;
  const int b = row0 >> 12;
  const int tid = threadIdx.x;
  const int w = tid >> 6, l = tid & 63, lr = l & 15, lq = l >> 4;

  __shared__ __attribute__((aligned(16))) char ring[4][4][2048];   // 32 KB
  __shared__ __attribute__((aligned(16))) unsigned short FpB[4][16][64]; // 8 KB

  char* ringw = &ring[w][0][0];
  auto ldsw = (__attribute__((address_space(3))) char*)&ring[w][0][0];

  const char* hb = (const char*)(H + (size_t)row0 * D_MODEL);
  const int srow = l >> 3;          // 0..7
  const int scol = (l & 7) * 16;    // byte within 128B row
  const int sxor = srow << 4;
  const int axor = (lr & 7) << 4;

  // ---------------- Phase 1 ----------------
  const unsigned short* wdb = Wd2 + (size_t)l * 8;
  f32x4 acc[4];
  acc[0] = acc[1] = acc[2] = acc[3] = (f32x4){0, 0, 0, 0};
  bf16x8 wd[4][4];

#define STG1(P, CH)                                                            \
  SB;                                                                          \
  {                                                                            \
    _Pragma("unroll") for (int i = 0; i < 2; ++i) {                            \
      const char* g = hb + (size_t)(8 * i + srow) * 16384 +                    \
                      (size_t)(w * 1024 + (CH) * 32) * 4 + (scol ^ sxor);      \
      __builtin_amdgcn_global_load_lds(                                        \
          (const __attribute__((address_space(1))) void*)g,                    \
          (__attribute__((address_space(3))) void*)(ldsw + (P) * 2048 +        \
                                                    i * 1024 + l * 16),        \
          16, 0, 0);                                                           \
    }                                                                          \
  }                                                                            \
  SB;                                                                          \
  {                                                                            \
    int sg4 = (w * 32 + (CH)) * 4;                                             \
    _Pragma("unroll") for (int nf = 0; nf < 4; ++nf)                           \
        wd[P][nf] = *(const bf16x8*)(wdb + (size_t)(sg4 + nf) * 512);          \
  }                                                                            \
  SB

#define CONS1(P)                                                               \
  {                                                                            \
    const char* rp = ringw + (P) * 2048 + lr * 128;                            \
    f32x4 p0 = *(const f32x4*)(rp + ((lq * 32) ^ axor));                       \
    f32x4 p1 = *(const f32x4*)(rp + ((lq * 32 + 16) ^ axor));                  \
    bf16x8 afr = cvt8(p0, p1);                                                 \
    _Pragma("unroll") for (int nf = 0; nf < 4; ++nf)                           \
        acc[nf] = __builtin_amdgcn_mfma_f32_16x16x32_bf16(afr, wd[P][nf],      \
                                                          acc[nf], 0, 0, 0);   \
  }

  STG1(0, 0); STG1(1, 1); STG1(2, 2); STG1(3, 3);
  for (int it = 0; it < 7; ++it) {
    const int ch = it * 4;
    WAITV(18); CONS1(0); STG1(0, ch + 4);
    WAITV(18); CONS1(1); STG1(1, ch + 5);
    WAITV(18); CONS1(2); STG1(2, ch + 6);
    WAITV(18); CONS1(3); STG1(3, ch + 7);
  }
  WAITV(18); CONS1(0);
  WAITV(12); CONS1(1);
  WAITV(6);  CONS1(2);
  WAITV(0);  CONS1(3);
#undef STG1
#undef CONS1

  // acc -> bf16 partials
#pragma unroll
  for (int nf = 0; nf < 4; ++nf)
#pragma unroll
    for (int rr = 0; rr < 4; ++rr)
      FpB[w][lq * 4 + rr][nf * 16 + lr] = f2bf(acc[nf][rr]);
  __syncthreads();
  // reduce: each thread owns (tok, 4 fibers); Fb aliases FpB[0]
  {
    const int tok = tid >> 4, f0 = (tid & 15) * 4;
    float s0 = 0, s1 = 0, s2 = 0, s3 = 0;
#pragma unroll
    for (int ww = 0; ww < 4; ++ww) {
      s0 += bf2f(FpB[ww][tok][f0 + 0]);
      s1 += bf2f(FpB[ww][tok][f0 + 1]);
      s2 += bf2f(FpB[ww][tok][f0 + 2]);
      s3 += bf2f(FpB[ww][tok][f0 + 3]);
    }
    FpB[0][tok][f0 + 0] = f2bf(s0);
    FpB[0][tok][f0 + 1] = f2bf(s1);
    FpB[0][tok][f0 + 2] = f2bf(s2);
    FpB[0][tok][f0 + 3] = f2bf(s3);
  }
  __syncthreads();

  // ---------------- Phase 2 ----------------
  bf16x8 fb0 = *(const bf16x8*)(&FpB[0][lr][lq * 8]);
  bf16x8 fb1 = *(const bf16x8*)(&FpB[0][lr][32 + lq * 8]);

  const unsigned short* ub = U2 + (((size_t)b * 256 + w * 64) * 64 + l) * 16;
  float* outb = Out + (size_t)row0 * D_MODEL;
  bf16x8 uu[4][4];

#define STG2(P, CH)                                                            \
  SB;                                                                          \
  {                                                                            \
    _Pragma("unroll") for (int i = 0; i < 2; ++i) {                            \
      const char* g = hb + (size_t)(8 * i + srow) * 16384 +                    \
                      (size_t)(w * 1024 + (CH) * 32) * 4 + (scol ^ sxor);      \
      __builtin_amdgcn_global_load_lds(                                        \
          (const __attribute__((address_space(1))) void*)g,                    \
          (__attribute__((address_space(3))) void*)(ldsw + (P) * 2048 +        \
                                                    i * 1024 + l * 16),        \
          16, 0, 0);                                                           \
    }                                                                          \
  }                                                                            \
  SB;                                                                          \
  {                                                                            \
    const unsigned short* up = ub + (size_t)(CH) * 2048;                       \
    uu[P][0] = *(const bf16x8*)(up);                                           \
    uu[P][1] = *(const bf16x8*)(up + 8);                                       \
    uu[P][2] = *(const bf16x8*)(up + 1024);                                    \
    uu[P][3] = *(const bf16x8*)(up + 1032);                                    \
  }                                                                            \
  SB

#define CONS2(P, CH)                                                           \
  {                                                                            \
    const char* rp = ringw + (P) * 2048 + lr * 128;                            \
    _Pragma("unroll") for (int ntl = 0; ntl < 2; ++ntl) {                      \
      f32x4 hr = *(const f32x4*)(rp + ((ntl * 64 + lq * 16) ^ axor));          \
      f32x4 c = {0, 0, 0, 0};                                                  \
      c = __builtin_amdgcn_mfma_f32_16x16x32_bf16(uu[P][2 * ntl], fb0, c, 0, 0, 0); \
      c = __builtin_amdgcn_mfma_f32_16x16x32_bf16(uu[P][2 * ntl + 1], fb1, c, 0, 0, 0); \
      *(f32x4*)(outb + (size_t)lr * D_MODEL + w * 1024 + (CH) * 32 +           \
                ntl * 16 + lq * 4) = hr + c;                                   \
    }                                                                          \
  }

  STG2(0, 0); STG2(1, 1); STG2(2, 2); STG2(3, 3);
  for (int it = 0; it < 7; ++it) {
    const int ch = it * 4;
    WAITV(18); CONS2(0, ch + 0); STG2(0, ch + 4);
    WAITV(18); CONS2(1, ch + 1); STG2(1, ch + 5);
    WAITV(18); CONS2(2, ch + 2); STG2(2, ch + 6);
    WAITV(18); CONS2(3, ch + 3); STG2(3, ch + 7);
  }
  WAITV(18); CONS2(0, 28);
  WAITV(12); CONS2(1, 29);
  WAITV(6);  CONS2(2, 30);
  WAITV(0);  CONS2(3, 31);
#undef STG2
#undef CONS2
}

// ---------------------------------------------------------------------------
extern "C" void kernel_launch(void* const* d_in, const int* in_sizes, int n_in,
                              void* d_out, int out_size, void* d_ws, size_t ws_size,
                              hipStream_t stream) {
  const float* h_t    = (const float*)d_in[0];
  // d_in[1] = z0 (unused by the reference)
  const float* A_u    = (const float*)d_in[2];
  const float* alpha  = (const float*)d_in[3];
  const float* W_down = (const float*)d_in[4];
  const float* W_up   = (const float*)d_in[5];
  float* out = (float*)d_out;

  char* ws = (char*)d_ws;
  float*          S   = (float*)ws;                               // 64 KiB
  unsigned short* Wd2 = (unsigned short*)(ws + (64 << 10));       // 512 KiB
  unsigned short* U2  = (unsigned short*)(ws + (576 << 10));      // 2 MiB

  prep1_kernel<<<NBATCH + 1024, 256, 0, stream>>>(A_u, W_down, S, Wd2);
  prep_u_kernel<<<512, 256, 0, stream>>>(W_up, S, alpha, U2);
  fused_kernel<<<NTOK / 16, 256, 0, stream>>>(h_t, Wd2, U2, out);
}

// Round 14
// 293.497 us; speedup vs baseline: 1.0045x; 1.0045x over previous
//
#include <hip/hip_runtime.h>
#include <hip/hip_bf16.h>
#include <cstdint>

#define D_MODEL 4096
#define NFIB    64
#define NBATCH  4
#define LSEQ    4096
#define NTOK    (NBATCH * LSEQ)

typedef __attribute__((ext_vector_type(4))) float f32x4;
typedef __attribute__((ext_vector_type(8))) short bf16x8;

__device__ __forceinline__ unsigned short f2bf(float f) {
  unsigned int u = __builtin_bit_cast(unsigned int, f);
  u += 0x7FFFu + ((u >> 16) & 1u);
  return (unsigned short)(u >> 16);
}
__device__ __forceinline__ float bf2f(unsigned short u) {
  return __builtin_bit_cast(float, (uint32_t)u << 16);
}
__device__ __forceinline__ bf16x8 cvt8(f32x4 a, f32x4 b) {
  union { __hip_bfloat162 h2[4]; bf16x8 v; } u;
  u.h2[0] = __float22bfloat162_rn(make_float2(a[0], a[1]));
  u.h2[1] = __float22bfloat162_rn(make_float2(a[2], a[3]));
  u.h2[2] = __float22bfloat162_rn(make_float2(b[0], b[1]));
  u.h2[3] = __float22bfloat162_rn(make_float2(b[2], b[3]));
  return u.v;
}

#define SB __builtin_amdgcn_sched_barrier(0)
#define WAITV(N)                                              \
  asm volatile("s_waitcnt vmcnt(" #N ")" ::: "memory");       \
  SB

// ---------------------------------------------------------------------------
// Blocks 0..3: S_b = Q_b - I = 2(I-A)^{-1}A.  Blocks 4..1027: Wd -> Wd2.
// ---------------------------------------------------------------------------
__global__ __launch_bounds__(256) void prep1_kernel(const float* __restrict__ A,
                                                    const float* __restrict__ Wd,
                                                    float* __restrict__ S,
                                                    unsigned short* __restrict__ Wd2) {
  const int blk = blockIdx.x;
  if (blk >= NBATCH) {
    int idx = (blk - NBATCH) * 256 + threadIdx.x;
    int j    = idx & 7;
    int lane = (idx >> 3) & 63;
    int nf   = (idx >> 9) & 3;
    int ks   = idx >> 11;
    int row = nf * 16 + (lane & 15);
    int col = ks * 32 + (lane >> 4) * 8 + j;
    Wd2[idx] = f2bf(Wd[row * D_MODEL + col]);
    return;
  }
  __shared__ float M[64][66];
  __shared__ float R[64][66];
  const int b = blk;
  const int tid = threadIdx.x;
  const int k = tid & 63;
  const int g = tid >> 6;
  const float* Ab = A + b * 4096;
#pragma unroll
  for (int ii = 0; ii < 16; ++ii) {
    int i = g * 16 + ii;
    float a = Ab[i * 64 + k];
    M[i][k] = ((i == k) ? 1.0f : 0.0f) - a;
    R[i][k] = 2.0f * a;
  }
  for (int j = 0; j < 64; ++j) {
    __syncthreads();
    float pr  = 1.0f / M[j][j];
    float mjk = M[j][k], rjk = R[j][k];
    float f[16];
#pragma unroll
    for (int ii = 0; ii < 16; ++ii) f[ii] = M[g * 16 + ii][j] * pr;
    __syncthreads();
#pragma unroll
    for (int ii = 0; ii < 16; ++ii) {
      int i = g * 16 + ii;
      if (i != j) { M[i][k] -= f[ii] * mjk; R[i][k] -= f[ii] * rjk; }
    }
  }
  __syncthreads();
  float* Sb = S + b * 4096;
#pragma unroll
  for (int ii = 0; ii < 16; ++ii) {
    int i = g * 16 + ii;
    Sb[i * 64 + k] = R[i][k] / M[i][i];
  }
}

// ---------------------------------------------------------------------------
// U2[(((b*256+nt)*64+lane)*2+h)*8+j] = bf16(alpha*(Wup@S)[d][f])
// ---------------------------------------------------------------------------
__global__ __launch_bounds__(256) void prep_u_kernel(const float* __restrict__ Wup,
                                                     const float* __restrict__ S,
                                                     const float* __restrict__ alpha_p,
                                                     unsigned short* __restrict__ U2) {
  __shared__ float Sl[4096];
  const int blk = blockIdx.x;          // 0..511
  const int b = blk >> 7;
  const int ntg = blk & 127;
  const float* Sb = S + b * 4096;
  for (int i = threadIdx.x; i < 1024; i += 256)
    ((f32x4*)Sl)[i] = ((const f32x4*)Sb)[i];
  __syncthreads();

  const int t = threadIdx.x;
  const int nt   = ntg * 2 + (t >> 7);
  const int h    = (t >> 6) & 1;
  const int lane = t & 63;
  const int d = nt * 16 + (lane & 15);
  const int fbase = h * 32 + (lane >> 4) * 8;
  const float alpha = alpha_p[0];
  const f32x4* wr = (const f32x4*)(Wup + d * 64);

  float s[8];
#pragma unroll
  for (int j = 0; j < 8; ++j) s[j] = 0.f;
#pragma unroll
  for (int g4 = 0; g4 < 16; ++g4) {
    f32x4 wv = wr[g4];
#pragma unroll
    for (int gg = 0; gg < 4; ++gg) {
      const float* srow = &Sl[(g4 * 4 + gg) * 64 + fbase];
      float wvg = wv[gg];
#pragma unroll
      for (int j = 0; j < 8; ++j) s[j] += wvg * srow[j];
    }
  }
  bf16x8 v;
#pragma unroll
  for (int j = 0; j < 8; ++j) v[j] = (short)f2bf(alpha * s[j]);
  *(bf16x8*)(U2 + ((((size_t)b * 256 + nt) * 64 + lane) * 2 + h) * 8) = v;
}

// ---------------------------------------------------------------------------
// Fused main. Identical to R13 EXCEPT: inside each staging group the
// register-destined L2 loads (wd/uu) are issued BEFORE the global_load_lds
// (HBM). vmcnt retires in order, so any compiler-inserted wait for the
// L2 registers no longer drains the HBM gload_lds queue behind it.
// Block = 16 tokens, 4 waves, grid 1024. Per-wave 4-slot rings, counted
// vmcnt(18) = 3 groups (6 events each) in flight.
// ---------------------------------------------------------------------------
__global__ __launch_bounds__(256, 4) void fused_kernel(
    const float* __restrict__ H, const unsigned short* __restrict__ Wd2,
    const unsigned short* __restrict__ U2, float* __restrict__ Out) {
  const int blk = blockIdx.x;
  const int row0 = blk * 16;
  const int b = row0 >> 12;
  const int tid = threadIdx.x;
  const int w = tid >> 6, l = tid & 63, lr = l & 15, lq = l >> 4;

  __shared__ __attribute__((aligned(16))) char ring[4][4][2048];   // 32 KB
  __shared__ __attribute__((aligned(16))) unsigned short FpB[4][16][64]; // 8 KB

  char* ringw = &ring[w][0][0];
  auto ldsw = (__attribute__((address_space(3))) char*)&ring[w][0][0];

  const char* hb = (const char*)(H + (size_t)row0 * D_MODEL);
  const int srow = l >> 3;          // 0..7
  const int scol = (l & 7) * 16;    // byte within 128B row
  const int sxor = srow << 4;
  const int axor = (lr & 7) << 4;

  // ---------------- Phase 1 ----------------
  const unsigned short* wdb = Wd2 + (size_t)l * 8;
  f32x4 acc[4];
  acc[0] = acc[1] = acc[2] = acc[3] = (f32x4){0, 0, 0, 0};
  bf16x8 wd[4][4];

#define STG1(P, CH)                                                            \
  SB;                                                                          \
  {                                                                            \
    int sg4 = (w * 32 + (CH)) * 4;                                             \
    _Pragma("unroll") for (int nf = 0; nf < 4; ++nf)                           \
        wd[P][nf] = *(const bf16x8*)(wdb + (size_t)(sg4 + nf) * 512);          \
  }                                                                            \
  SB;                                                                          \
  {                                                                            \
    _Pragma("unroll") for (int i = 0; i < 2; ++i) {                            \
      const char* g = hb + (size_t)(8 * i + srow) * 16384 +                    \
                      (size_t)(w * 1024 + (CH) * 32) * 4 + (scol ^ sxor);      \
      __builtin_amdgcn_global_load_lds(                                        \
          (const __attribute__((address_space(1))) void*)g,                    \
          (__attribute__((address_space(3))) void*)(ldsw + (P) * 2048 +        \
                                                    i * 1024 + l * 16),        \
          16, 0, 0);                                                           \
    }                                                                          \
  }                                                                            \
  SB

#define CONS1(P)                                                               \
  {                                                                            \
    const char* rp = ringw + (P) * 2048 + lr * 128;                            \
    f32x4 p0 = *(const f32x4*)(rp + ((lq * 32) ^ axor));                       \
    f32x4 p1 = *(const f32x4*)(rp + ((lq * 32 + 16) ^ axor));                  \
    bf16x8 afr = cvt8(p0, p1);                                                 \
    _Pragma("unroll") for (int nf = 0; nf < 4; ++nf)                           \
        acc[nf] = __builtin_amdgcn_mfma_f32_16x16x32_bf16(afr, wd[P][nf],      \
                                                          acc[nf], 0, 0, 0);   \
  }

  STG1(0, 0); STG1(1, 1); STG1(2, 2); STG1(3, 3);
  for (int it = 0; it < 7; ++it) {
    const int ch = it * 4;
    WAITV(18); CONS1(0); STG1(0, ch + 4);
    WAITV(18); CONS1(1); STG1(1, ch + 5);
    WAITV(18); CONS1(2); STG1(2, ch + 6);
    WAITV(18); CONS1(3); STG1(3, ch + 7);
  }
  WAITV(18); CONS1(0);
  WAITV(12); CONS1(1);
  WAITV(6);  CONS1(2);
  WAITV(0);  CONS1(3);
#undef STG1
#undef CONS1

  // acc -> bf16 partials
#pragma unroll
  for (int nf = 0; nf < 4; ++nf)
#pragma unroll
    for (int rr = 0; rr < 4; ++rr)
      FpB[w][lq * 4 + rr][nf * 16 + lr] = f2bf(acc[nf][rr]);
  __syncthreads();
  // reduce: each thread owns (tok, 4 fibers); result into FpB[0]
  {
    const int tok = tid >> 4, f0 = (tid & 15) * 4;
    float s0 = 0, s1 = 0, s2 = 0, s3 = 0;
#pragma unroll
    for (int ww = 0; ww < 4; ++ww) {
      s0 += bf2f(FpB[ww][tok][f0 + 0]);
      s1 += bf2f(FpB[ww][tok][f0 + 1]);
      s2 += bf2f(FpB[ww][tok][f0 + 2]);
      s3 += bf2f(FpB[ww][tok][f0 + 3]);
    }
    FpB[0][tok][f0 + 0] = f2bf(s0);
    FpB[0][tok][f0 + 1] = f2bf(s1);
    FpB[0][tok][f0 + 2] = f2bf(s2);
    FpB[0][tok][f0 + 3] = f2bf(s3);
  }
  __syncthreads();

  // ---------------- Phase 2 ----------------
  bf16x8 fb0 = *(const bf16x8*)(&FpB[0][lr][lq * 8]);
  bf16x8 fb1 = *(const bf16x8*)(&FpB[0][lr][32 + lq * 8]);

  const unsigned short* ub = U2 + (((size_t)b * 256 + w * 64) * 64 + l) * 16;
  float* outb = Out + (size_t)row0 * D_MODEL;
  bf16x8 uu[4][4];

#define STG2(P, CH)                                                            \
  SB;                                                                          \
  {                                                                            \
    const unsigned short* up = ub + (size_t)(CH) * 2048;                       \
    uu[P][0] = *(const bf16x8*)(up);                                           \
    uu[P][1] = *(const bf16x8*)(up + 8);                                       \
    uu[P][2] = *(const bf16x8*)(up + 1024);                                    \
    uu[P][3] = *(const bf16x8*)(up + 1032);                                    \
  }                                                                            \
  SB;                                                                          \
  {                                                                            \
    _Pragma("unroll") for (int i = 0; i < 2; ++i) {                            \
      const char* g = hb + (size_t)(8 * i + srow) * 16384 +                    \
                      (size_t)(w * 1024 + (CH) * 32) * 4 + (scol ^ sxor);      \
      __builtin_amdgcn_global_load_lds(                                        \
          (const __attribute__((address_space(1))) void*)g,                    \
          (__attribute__((address_space(3))) void*)(ldsw + (P) * 2048 +        \
                                                    i * 1024 + l * 16),        \
          16, 0, 0);                                                           \
    }                                                                          \
  }                                                                            \
  SB

#define CONS2(P, CH)                                                           \
  {                                                                            \
    const char* rp = ringw + (P) * 2048 + lr * 128;                            \
    _Pragma("unroll") for (int ntl = 0; ntl < 2; ++ntl) {                      \
      f32x4 hr = *(const f32x4*)(rp + ((ntl * 64 + lq * 16) ^ axor));          \
      f32x4 c = {0, 0, 0, 0};                                                  \
      c = __builtin_amdgcn_mfma_f32_16x16x32_bf16(uu[P][2 * ntl], fb0, c, 0, 0, 0); \
      c = __builtin_amdgcn_mfma_f32_16x16x32_bf16(uu[P][2 * ntl + 1], fb1, c, 0, 0, 0); \
      *(f32x4*)(outb + (size_t)lr * D_MODEL + w * 1024 + (CH) * 32 +           \
                ntl * 16 + lq * 4) = hr + c;                                   \
    }                                                                          \
  }

  STG2(0, 0); STG2(1, 1); STG2(2, 2); STG2(3, 3);
  for (int it = 0; it < 7; ++it) {
    const int ch = it * 4;
    WAITV(18); CONS2(0, ch + 0); STG2(0, ch + 4);
    WAITV(18); CONS2(1, ch + 1); STG2(1, ch + 5);
    WAITV(18); CONS2(2, ch + 2); STG2(2, ch + 6);
    WAITV(18); CONS2(3, ch + 3); STG2(3, ch + 7);
  }
  WAITV(18); CONS2(0, 28);
  WAITV(12); CONS2(1, 29);
  WAITV(6);  CONS2(2, 30);
  WAITV(0);  CONS2(3, 31);
#undef STG2
#undef CONS2
}

// ---------------------------------------------------------------------------
extern "C" void kernel_launch(void* const* d_in, const int* in_sizes, int n_in,
                              void* d_out, int out_size, void* d_ws, size_t ws_size,
                              hipStream_t stream) {
  const float* h_t    = (const float*)d_in[0];
  // d_in[1] = z0 (unused by the reference)
  const float* A_u    = (const float*)d_in[2];
  const float* alpha  = (const float*)d_in[3];
  const float* W_down = (const float*)d_in[4];
  const float* W_up   = (const float*)d_in[5];
  float* out = (float*)d_out;

  char* ws = (char*)d_ws;
  float*          S   = (float*)ws;                               // 64 KiB
  unsigned short* Wd2 = (unsigned short*)(ws + (64 << 10));       // 512 KiB
  unsigned short* U2  = (unsigned short*)(ws + (576 << 10));      // 2 MiB

  prep1_kernel<<<NBATCH + 1024, 256, 0, stream>>>(A_u, W_down, S, Wd2);
  prep_u_kernel<<<512, 256, 0, stream>>>(W_up, S, alpha, U2);
  fused_kernel<<<NTOK / 16, 256, 0, stream>>>(h_t, Wd2, U2, out);
}